// Round 1
// baseline (392.204 us; speedup 1.0000x reference)
//
#include <hip/hip_runtime.h>
#include <stdint.h>

typedef unsigned short u16;
typedef __attribute__((ext_vector_type(8))) short bf16x8;
typedef __attribute__((ext_vector_type(4))) float f32x4;

#define S_LEN 4096
#define HID_DIM 2304
#define NH 8
#define NKV 4
#define HD 256
#define QKV_N 4096
#define AO_N 2048
#define WIN 1024
#define QSCALE 0.0625f

static __device__ __forceinline__ u16 f2bf(float f) {
  union { float f; uint32_t u; } v; v.f = f;
  return (u16)((v.u + 0x7FFFu + ((v.u >> 16) & 1u)) >> 16);
}
static __device__ __forceinline__ float bf2f(u16 h) {
  union { uint32_t u; float f; } v; v.u = ((uint32_t)h) << 16;
  return v.f;
}

// ---------------- fp32 -> bf16 elementwise ----------------
__global__ __launch_bounds__(256) void k_cvt_bf16(const float* __restrict__ in,
                                                  u16* __restrict__ out, int n) {
  int i = (blockIdx.x * 256 + threadIdx.x) * 4;
  if (i >= n) return;
  float4 v = *(const float4*)(in + i);
  uint64_t p = (uint64_t)f2bf(v.x) | ((uint64_t)f2bf(v.y) << 16)
             | ((uint64_t)f2bf(v.z) << 32) | ((uint64_t)f2bf(v.w) << 48);
  *(uint64_t*)(out + i) = p;
}

// in: fp32 [R][C] row-major; out bf16: out[(row_off + c)*out_stride + r] = in[r][c]
// grid = (C/32, R/32), 256 threads
__global__ __launch_bounds__(256) void k_transpose_cvt(const float* __restrict__ in, int C,
                                                       u16* __restrict__ out, int out_stride,
                                                       int row_off) {
  __shared__ float tile[32][33];
  int c0 = blockIdx.x * 32, r0 = blockIdx.y * 32;
  int tx = threadIdx.x & 31, ty = threadIdx.x >> 5;
#pragma unroll
  for (int i = 0; i < 4; i++)
    tile[ty + i * 8][tx] = in[(size_t)(r0 + ty + i * 8) * C + c0 + tx];
  __syncthreads();
#pragma unroll
  for (int i = 0; i < 4; i++)
    out[(size_t)(row_off + c0 + ty + i * 8) * out_stride + r0 + tx] = f2bf(tile[tx][ty + i * 8]);
}

// ---------------- bf16 GEMM: C[M][N] = A[M][K] * Bt[N][K]^T ----------------
// 128x128 tile, BK=32, 256 thr = 4 waves (2x2), each wave 64x64 via 4x4 16x16x32 MFMA frags.
template <int OUT_BF16>
__global__ __launch_bounds__(256) void k_gemm_bt(const u16* __restrict__ A,
                                                 const u16* __restrict__ Bt,
                                                 void* __restrict__ Cout,
                                                 int M, int N, int K) {
  __shared__ u16 lA[128 * 32];
  __shared__ u16 lB[128 * 32];
  const int t = threadIdx.x;
  const int lane = t & 63, wave = t >> 6;
  const int wm = wave >> 1, wn = wave & 1;
  const int bm = blockIdx.y, bn = blockIdx.x;
  const int l15 = lane & 15, l4 = lane >> 4;
  f32x4 acc[4][4] = {};
  const int arow = t >> 2, akk = (t & 3) * 8;
  const u16* Ab = A + (size_t)bm * 128 * K + (size_t)arow * K + akk;
  const u16* Bb = Bt + (size_t)bn * 128 * K + (size_t)arow * K + akk;
  for (int k0 = 0; k0 < K; k0 += 32) {
    __syncthreads();
    bf16x8 a0 = *(const bf16x8*)(Ab + k0);
    bf16x8 a1 = *(const bf16x8*)(Ab + (size_t)64 * K + k0);
    bf16x8 b0 = *(const bf16x8*)(Bb + k0);
    bf16x8 b1 = *(const bf16x8*)(Bb + (size_t)64 * K + k0);
    *(bf16x8*)&lA[arow * 32 + akk] = a0;
    *(bf16x8*)&lA[(arow + 64) * 32 + akk] = a1;
    *(bf16x8*)&lB[arow * 32 + akk] = b0;
    *(bf16x8*)&lB[(arow + 64) * 32 + akk] = b1;
    __syncthreads();
    bf16x8 af[4], bfr[4];
#pragma unroll
    for (int i = 0; i < 4; i++)
      af[i] = *(const bf16x8*)&lA[(wm * 64 + i * 16 + l15) * 32 + l4 * 8];
#pragma unroll
    for (int j = 0; j < 4; j++)
      bfr[j] = *(const bf16x8*)&lB[(wn * 64 + j * 16 + l15) * 32 + l4 * 8];
#pragma unroll
    for (int i = 0; i < 4; i++)
#pragma unroll
      for (int j = 0; j < 4; j++)
        acc[i][j] = __builtin_amdgcn_mfma_f32_16x16x32_bf16(af[i], bfr[j], acc[i][j], 0, 0, 0);
  }
#pragma unroll
  for (int i = 0; i < 4; i++)
#pragma unroll
    for (int j = 0; j < 4; j++)
#pragma unroll
      for (int r = 0; r < 4; r++) {
        size_t row = bm * 128 + wm * 64 + i * 16 + l4 * 4 + r;
        size_t col = bn * 128 + wn * 64 + j * 16 + l15;
        if (OUT_BF16)
          ((u16*)Cout)[row * N + col] = f2bf(acc[i][j][r]);
        else
          ((float*)Cout)[row * N + col] = acc[i][j][r];
      }
}

// ---------------- fused RMSNorm + RoPE + scale, in place on bf16 qkv ----------------
// one block (128 thr) per (s, head) row; 12 rows per s: 8 q heads + 4 k heads
__global__ __launch_bounds__(128) void k_normrope(u16* __restrict__ qkv,
                                                  const int* __restrict__ pos_ids,
                                                  const float* __restrict__ qw,
                                                  const float* __restrict__ kw) {
  __shared__ float cross[2];
  int idx = blockIdx.x;
  int s = idx / 12, r = idx % 12;
  bool is_q = (r < 8);
  u16* p = qkv + (size_t)s * QKV_N + (is_q ? r * HD : 2048 + (r - 8) * HD);
  const float* w = is_q ? qw : kw;
  int j = threadIdx.x;  // 0..127
  float x1 = bf2f(p[j]), x2 = bf2f(p[j + 128]);
  float ss = x1 * x1 + x2 * x2;
#pragma unroll
  for (int off = 1; off < 64; off <<= 1) ss += __shfl_xor(ss, off);
  if ((threadIdx.x & 63) == 0) cross[threadIdx.x >> 6] = ss;
  __syncthreads();
  float rms = rsqrtf((cross[0] + cross[1]) * (1.0f / 256.0f) + 1e-6f);
  float y1 = x1 * rms * (1.0f + w[j]);
  float y2 = x2 * rms * (1.0f + w[j + 128]);
  // inv_freq_j = theta^(-j/128) ; log2(10000) = 13.287712379549449
  float ang = (float)pos_ids[s] * exp2f((float)j * (-13.287712379549449f / 128.0f));
  float sn, c;
  sincosf(ang, &sn, &c);
  float sc = is_q ? QSCALE : 1.0f;
  p[j] = f2bf((y1 * c - y2 * sn) * sc);
  p[j + 128] = f2bf((y1 * sn + y2 * c) * sc);
}

// ---------------- flash attention, sliding window, GQA ----------------
// block = (64 queries, 1 head), 256 thr = 4 waves x 16 q-rows; 32-key tiles
__global__ __launch_bounds__(256) void k_attn(const u16* __restrict__ qkv,
                                              const int* __restrict__ pos_ids,
                                              u16* __restrict__ aout) {
  __shared__ u16 lK[32 * 264];    // [key][256 + 8 pad]
  __shared__ u16 lVt[256 * 48];   // [d][32 + 16 pad] (transposed V)
  __shared__ u16 lP[4 * 16 * 32]; // per-wave P tiles
  const int h = blockIdx.y;
  const int q0 = blockIdx.x * 64;
  const int kvh = h >> 1;
  const int t = threadIdx.x, lane = t & 63, wave = t >> 6;
  const int l15 = lane & 15, l4 = lane >> 4;

  // Q fragments in registers (A-layout: row = lane&15, k = (lane>>4)*8+j)
  bf16x8 qf[8];
  {
    const u16* qptr = qkv + (size_t)(q0 + wave * 16 + l15) * QKV_N + h * HD + l4 * 8;
#pragma unroll
    for (int kc = 0; kc < 8; kc++) qf[kc] = *(const bf16x8*)(qptr + kc * 32);
  }
  f32x4 acc[16] = {};
  float mrow[4], lrow[4];
#pragma unroll
  for (int r = 0; r < 4; r++) { mrow[r] = -1e30f; lrow[r] = 0.0f; }
  int qi[4];
#pragma unroll
  for (int r = 0; r < 4; r++) qi[r] = pos_ids[q0 + wave * 16 + l4 * 4 + r];

  int start = q0 - (WIN - 1);
  if (start < 0) start = 0;
  start &= ~31;
  const int skey = t >> 3, sc8 = t & 7;
  for (int t0 = start; t0 <= q0 + 63; t0 += 32) {
    // stage K [32][256] and V transposed [256][32]
    const u16* kbase = qkv + (size_t)(t0 + skey) * QKV_N + 2048 + kvh * HD;
    const u16* vbase = kbase + 1024;
#pragma unroll
    for (int pass = 0; pass < 4; pass++) {
      int d0 = sc8 * 8 + pass * 64;
      *(bf16x8*)&lK[skey * 264 + d0] = *(const bf16x8*)(kbase + d0);
      bf16x8 vv = *(const bf16x8*)(vbase + d0);
#pragma unroll
      for (int jj = 0; jj < 8; jj++) lVt[(d0 + jj) * 48 + skey] = (u16)vv[jj];
    }
    __syncthreads();
    // S = Q K^T : two 16-key column blocks
    f32x4 sfr[2];
#pragma unroll
    for (int n = 0; n < 2; n++) {
      f32x4 sv = {};
#pragma unroll
      for (int kc = 0; kc < 8; kc++) {
        bf16x8 kf = *(const bf16x8*)&lK[(n * 16 + l15) * 264 + kc * 32 + l4 * 8];
        sv = __builtin_amdgcn_mfma_f32_16x16x32_bf16(qf[kc], kf, sv, 0, 0, 0);
      }
      sfr[n] = sv;
    }
    int kp0 = pos_ids[t0 + l15];
    int kp1 = pos_ids[t0 + 16 + l15];
    float p0[4], p1[4];
#pragma unroll
    for (int r = 0; r < 4; r++) {
      int pi = qi[r];
      float s0 = ((kp0 <= pi) && (pi - kp0 < WIN)) ? sfr[0][r] : -__builtin_inff();
      float s1 = ((kp1 <= pi) && (pi - kp1 < WIN)) ? sfr[1][r] : -__builtin_inff();
      float mx = fmaxf(s0, s1);
#pragma unroll
      for (int off = 1; off < 16; off <<= 1) mx = fmaxf(mx, __shfl_xor(mx, off));
      float newm = fmaxf(mrow[r], mx);
      float alpha = __expf(mrow[r] - newm);
      float e0 = __expf(s0 - newm), e1 = __expf(s1 - newm);
      float sum = e0 + e1;
#pragma unroll
      for (int off = 1; off < 16; off <<= 1) sum += __shfl_xor(sum, off);
      lrow[r] = lrow[r] * alpha + sum;
      mrow[r] = newm;
#pragma unroll
      for (int nd = 0; nd < 16; nd++) acc[nd][r] *= alpha;
      p0[r] = e0;
      p1[r] = e1;
    }
    // P -> per-wave LDS (C-layout write), reread in A-layout (same-wave DS is in-order)
#pragma unroll
    for (int r = 0; r < 4; r++) {
      lP[wave * 512 + (l4 * 4 + r) * 32 + l15] = f2bf(p0[r]);
      lP[wave * 512 + (l4 * 4 + r) * 32 + 16 + l15] = f2bf(p1[r]);
    }
    bf16x8 pa = *(const bf16x8*)&lP[wave * 512 + l15 * 32 + l4 * 8];
#pragma unroll
    for (int nd = 0; nd < 16; nd++) {
      bf16x8 vf = *(const bf16x8*)&lVt[(nd * 16 + l15) * 48 + l4 * 8];
      acc[nd] = __builtin_amdgcn_mfma_f32_16x16x32_bf16(pa, vf, acc[nd], 0, 0, 0);
    }
    __syncthreads();
  }
#pragma unroll
  for (int r = 0; r < 4; r++) lrow[r] = 1.0f / lrow[r];
#pragma unroll
  for (int nd = 0; nd < 16; nd++)
#pragma unroll
    for (int r = 0; r < 4; r++) {
      size_t row = q0 + wave * 16 + l4 * 4 + r;
      aout[row * AO_N + h * HD + nd * 16 + l15] = f2bf(acc[nd][r] * lrow[r]);
    }
}

extern "C" void kernel_launch(void* const* d_in, const int* in_sizes, int n_in,
                              void* d_out, int out_size, void* d_ws, size_t ws_size,
                              hipStream_t stream) {
  const float* x = (const float*)d_in[0];
  const int* pos = (const int*)d_in[1];
  const float* wq = (const float*)d_in[2];
  const float* wk = (const float*)d_in[3];
  const float* wv = (const float*)d_in[4];
  const float* wo = (const float*)d_in[5];
  const float* qnw = (const float*)d_in[6];
  const float* knw = (const float*)d_in[7];

  // scratch layout:
  //   qkv bf16 [4096][4096] lives in d_out (33.5MB of its 37.7MB; overwritten by final GEMM)
  //   ws + 0        : x bf16 [4096][2304] (later reused as attn_out bf16 [4096][2048])
  //   ws + 18874368 : stacked W^T bf16 (wq|wk|wv -> [4096][2304], later wo^T [2304][2048])
  u16* qkv = (u16*)d_out;
  u16* xbf = (u16*)d_ws;
  u16* wT = (u16*)((char*)d_ws + 18874368);
  u16* aout = xbf;

  k_cvt_bf16<<<9216, 256, 0, stream>>>(x, xbf, S_LEN * HID_DIM);
  {
    dim3 g(2048 / 32, HID_DIM / 32);
    k_transpose_cvt<<<g, 256, 0, stream>>>(wq, 2048, wT, HID_DIM, 0);
  }
  {
    dim3 g(1024 / 32, HID_DIM / 32);
    k_transpose_cvt<<<g, 256, 0, stream>>>(wk, 1024, wT, HID_DIM, 2048);
    k_transpose_cvt<<<g, 256, 0, stream>>>(wv, 1024, wT, HID_DIM, 3072);
  }
  {
    dim3 g(QKV_N / 128, S_LEN / 128);
    k_gemm_bt<1><<<g, 256, 0, stream>>>(xbf, wT, qkv, S_LEN, QKV_N, HID_DIM);
  }
  k_normrope<<<S_LEN * 12, 128, 0, stream>>>(qkv, pos, qnw, knw);
  {
    dim3 g(S_LEN / 64, NH);
    k_attn<<<g, 256, 0, stream>>>(qkv, pos, aout);
  }
  {
    dim3 g(HID_DIM / 32, 2048 / 32);
    k_transpose_cvt<<<g, 256, 0, stream>>>(wo, HID_DIM, wT, 2048, 0);
  }
  {
    dim3 g(HID_DIM / 128, S_LEN / 128);
    k_gemm_bt<0><<<g, 256, 0, stream>>>(aout, wT, d_out, S_LEN, HID_DIM, 2048);
  }
}

// Round 2
// 380.013 us; speedup vs baseline: 1.0321x; 1.0321x over previous
//
#include <hip/hip_runtime.h>
#include <stdint.h>

typedef unsigned short u16;
typedef __attribute__((ext_vector_type(8))) short bf16x8;
typedef __attribute__((ext_vector_type(4))) float f32x4;

#define S_LEN 4096
#define HID_DIM 2304
#define QKV_N 4096
#define AO_N 2048
#define HD 256
#define WIN 1024
#define QSCALE 0.0625f

static __device__ __forceinline__ u16 f2bf(float f) {
  union { float f; uint32_t u; } v; v.f = f;
  return (u16)((v.u + 0x7FFFu + ((v.u >> 16) & 1u)) >> 16);
}
static __device__ __forceinline__ float bf2f(u16 h) {
  union { uint32_t u; float f; } v; v.u = ((uint32_t)h) << 16;
  return v.f;
}

static __device__ __forceinline__ void gld16(const void* src, void* dst) {
  __builtin_amdgcn_global_load_lds((const __attribute__((address_space(1))) void*)src,
                                   (__attribute__((address_space(3))) void*)dst, 16, 0, 0);
}

// ---------------- fp32 -> bf16 elementwise ----------------
__global__ __launch_bounds__(256) void k_cvt_bf16(const float* __restrict__ in,
                                                  u16* __restrict__ out, int n) {
  int i = (blockIdx.x * 256 + threadIdx.x) * 4;
  if (i >= n) return;
  float4 v = *(const float4*)(in + i);
  uint64_t p = (uint64_t)f2bf(v.x) | ((uint64_t)f2bf(v.y) << 16)
             | ((uint64_t)f2bf(v.z) << 32) | ((uint64_t)f2bf(v.w) << 48);
  *(uint64_t*)(out + i) = p;
}

// in: fp32 [R][C] row-major; out bf16: out[(row_off + c)*out_stride + r] = in[r][c]
__global__ __launch_bounds__(256) void k_transpose_cvt(const float* __restrict__ in, int C,
                                                       u16* __restrict__ out, int out_stride,
                                                       int row_off) {
  __shared__ float tile[32][33];
  int c0 = blockIdx.x * 32, r0 = blockIdx.y * 32;
  int tx = threadIdx.x & 31, ty = threadIdx.x >> 5;
#pragma unroll
  for (int i = 0; i < 4; i++)
    tile[ty + i * 8][tx] = in[(size_t)(r0 + ty + i * 8) * C + c0 + tx];
  __syncthreads();
#pragma unroll
  for (int i = 0; i < 4; i++)
    out[(size_t)(row_off + c0 + ty + i * 8) * out_stride + r0 + tx] = f2bf(tile[tx][ty + i * 8]);
}

// ---------------- bf16 transpose of V block of qkv -> vt[kv*256 + d][s] ----------------
__global__ __launch_bounds__(256) void k_vtrans(const u16* __restrict__ qkv,
                                                u16* __restrict__ vtout) {
  __shared__ u16 tile[32][33];
  int c0 = blockIdx.x * 32, s0 = blockIdx.y * 32;
  int tx = threadIdx.x & 31, ty = threadIdx.x >> 5;
#pragma unroll
  for (int i = 0; i < 4; i++)
    tile[ty + i * 8][tx] = qkv[(size_t)(s0 + ty + i * 8) * QKV_N + 3072 + c0 + tx];
  __syncthreads();
#pragma unroll
  for (int i = 0; i < 4; i++)
    vtout[(size_t)(c0 + ty + i * 8) * S_LEN + s0 + tx] = tile[tx][ty + i * 8];
}

// ---------------- bf16 GEMM: C[M][N] = A[M][K] * Bt[N][K]^T ----------------
// 128x128 tile, BK=32, 4 waves (2x2); global_load_lds width-16 staging (m97 pattern)
template <int OUT_BF16>
__global__ __launch_bounds__(256) void k_gemm_bt(const u16* __restrict__ A,
                                                 const u16* __restrict__ Bt,
                                                 void* __restrict__ Cout,
                                                 int M, int N, int K) {
  __shared__ u16 lA[128 * 32];
  __shared__ u16 lB[128 * 32];
  const int t = threadIdx.x;
  const int lane = t & 63, wave = t >> 6;
  const int wm = wave >> 1, wn = wave & 1;
  const int bm = blockIdx.y, bn = blockIdx.x;
  const int l15 = lane & 15, l4 = lane >> 4;
  f32x4 acc[4][4] = {};
  // staging: wave w stages rows [w*32, w*32+32) of both tiles; lane -> (row, 16B slot)
  const int srow = wave * 32 + (lane >> 2), scol = (lane & 3) * 8;
  const u16* Ab = A + (size_t)(bm * 128 + srow) * K + scol;
  const u16* Bb = Bt + (size_t)(bn * 128 + srow) * K + scol;
  u16* lA0 = &lA[wave * 1024];
  u16* lB0 = &lB[wave * 1024];
  for (int k0 = 0; k0 < K; k0 += 32) {
    __syncthreads();
    gld16(Ab + k0, lA0);
    gld16(Ab + (size_t)16 * K + k0, lA0 + 512);
    gld16(Bb + k0, lB0);
    gld16(Bb + (size_t)16 * K + k0, lB0 + 512);
    __syncthreads();  // drains vmcnt -> staged data visible
    bf16x8 af[4], bfr[4];
#pragma unroll
    for (int i = 0; i < 4; i++)
      af[i] = *(const bf16x8*)&lA[(wm * 64 + i * 16 + l15) * 32 + l4 * 8];
#pragma unroll
    for (int j = 0; j < 4; j++)
      bfr[j] = *(const bf16x8*)&lB[(wn * 64 + j * 16 + l15) * 32 + l4 * 8];
#pragma unroll
    for (int i = 0; i < 4; i++)
#pragma unroll
      for (int j = 0; j < 4; j++)
        acc[i][j] = __builtin_amdgcn_mfma_f32_16x16x32_bf16(af[i], bfr[j], acc[i][j], 0, 0, 0);
  }
#pragma unroll
  for (int i = 0; i < 4; i++)
#pragma unroll
    for (int j = 0; j < 4; j++)
#pragma unroll
      for (int r = 0; r < 4; r++) {
        size_t row = bm * 128 + wm * 64 + i * 16 + l4 * 4 + r;
        size_t col = bn * 128 + wn * 64 + j * 16 + l15;
        if (OUT_BF16)
          ((u16*)Cout)[row * N + col] = f2bf(acc[i][j][r]);
        else
          ((float*)Cout)[row * N + col] = acc[i][j][r];
      }
}

// ---------------- fused RMSNorm + RoPE + scale, in place on bf16 q/k ----------------
__global__ __launch_bounds__(128) void k_normrope(u16* __restrict__ qkv,
                                                  const int* __restrict__ pos_ids,
                                                  const float* __restrict__ qw,
                                                  const float* __restrict__ kw) {
  __shared__ float cross[2];
  int idx = blockIdx.x;
  int s = idx / 12, r = idx % 12;
  bool is_q = (r < 8);
  u16* p = qkv + (size_t)s * QKV_N + (is_q ? r * HD : 2048 + (r - 8) * HD);
  const float* w = is_q ? qw : kw;
  int j = threadIdx.x;  // 0..127
  float x1 = bf2f(p[j]), x2 = bf2f(p[j + 128]);
  float ss = x1 * x1 + x2 * x2;
#pragma unroll
  for (int off = 1; off < 64; off <<= 1) ss += __shfl_xor(ss, off);
  if ((threadIdx.x & 63) == 0) cross[threadIdx.x >> 6] = ss;
  __syncthreads();
  float rms = rsqrtf((cross[0] + cross[1]) * (1.0f / 256.0f) + 1e-6f);
  float y1 = x1 * rms * (1.0f + w[j]);
  float y2 = x2 * rms * (1.0f + w[j + 128]);
  float ang = (float)pos_ids[s] * exp2f((float)j * (-13.287712379549449f / 128.0f));
  float sn, c;
  sincosf(ang, &sn, &c);
  float sc = is_q ? QSCALE : 1.0f;
  p[j] = f2bf((y1 * c - y2 * sn) * sc);
  p[j + 128] = f2bf((y1 * sn + y2 * c) * sc);
}

// ---------------- flash attention v2: sliding window, GQA ----------------
// block = (128 q, 1 head), 4 waves x 32 q-rows (2 A-frags), KVBLK=64, dbuf K/V via
// global_load_lds with pre-swizzled source; XOR swizzle (row&7)<<4 on all strided reads.
__global__ __launch_bounds__(256, 1) void k_attn(const u16* __restrict__ qkv,
                                                 const u16* __restrict__ vt,
                                                 const int* __restrict__ pos_ids,
                                                 u16* __restrict__ aout) {
  __shared__ u16 lK[2][64 * 256];   // [key][d], rows 512B, swizzled
  __shared__ u16 lV[2][256 * 64];   // [d][key], rows 128B, swizzled
  __shared__ u16 lP[4][32 * 64];    // per-wave P, rows 128B, swizzled
  const int h = blockIdx.y;
  const int q0 = blockIdx.x * 128;
  const int kvh = h >> 1;
  const int t = threadIdx.x, lane = t & 63, wave = t >> 6;
  const int l15 = lane & 15, l4 = lane >> 4;
  const int qw = q0 + wave * 32;

  // Q fragments [qf][kc] (A-layout: row=lane&15, k=(lane>>4)*8+j)
  bf16x8 qfr[2][8];
#pragma unroll
  for (int f = 0; f < 2; f++) {
    const u16* qptr = qkv + (size_t)(qw + f * 16 + l15) * QKV_N + h * HD + l4 * 8;
#pragma unroll
    for (int kc = 0; kc < 8; kc++) qfr[f][kc] = *(const bf16x8*)(qptr + kc * 32);
  }
  f32x4 acc[2][16] = {};
  float mrow[2][4], lrow[2][4];
#pragma unroll
  for (int f = 0; f < 2; f++)
#pragma unroll
    for (int r = 0; r < 4; r++) { mrow[f][r] = -1e30f; lrow[f][r] = 0.0f; }
  int qi[2][4];
#pragma unroll
  for (int f = 0; f < 2; f++)
#pragma unroll
    for (int r = 0; r < 4; r++) qi[f][r] = pos_ids[qw + f * 16 + l4 * 4 + r];

  // staging lane maps: K chunk=1KB=2 rows x 512B; V chunk=1KB=8 rows x 128B
  const int krw = lane >> 5, kcl = lane & 31;
  const int vrw = lane >> 3, vcl = lane & 7;
  const u16* kgb = qkv + 2048 + kvh * HD;
  const u16* vgb = vt + (size_t)kvh * HD * S_LEN;

  int start = q0 - (WIN - 1);
  if (start < 0) start = 0;
  start &= ~63;

#define ATTN_STAGE(B, T0) do {                                                        \
    _Pragma("unroll")                                                                 \
    for (int i_ = 0; i_ < 8; i_++) {                                                  \
      int ch_ = wave * 8 + i_;                                                        \
      int kr_ = ch_ * 2 + krw;                                                        \
      gld16(kgb + (size_t)((T0) + kr_) * QKV_N + ((kcl ^ (kr_ & 7)) * 8),             \
            &lK[B][ch_ * 512]);                                                       \
      int vr_ = ch_ * 8 + vrw;                                                        \
      gld16(vgb + (size_t)vr_ * S_LEN + (T0) + ((vcl ^ (vr_ & 7)) * 8),               \
            &lV[B][ch_ * 512]);                                                       \
    }                                                                                 \
  } while (0)

  ATTN_STAGE(0, start);
  __syncthreads();
  int buf = 0;
  for (int t0 = start; t0 <= q0 + 127; t0 += 64) {
    if (t0 + 64 <= q0 + 127) { int nb = buf ^ 1; ATTN_STAGE(nb, t0 + 64); }
    // ---- S = Q K^T (4 key-blocks of 16) ----
    f32x4 sv[2][4] = {};
#pragma unroll
    for (int kb = 0; kb < 4; kb++) {
      const char* krow = (const char*)&lK[buf][(kb * 16 + l15) * 256];
      const int sw = ((kb * 16 + l15) & 7) << 4;
#pragma unroll
      for (int kc = 0; kc < 8; kc++) {
        bf16x8 kf = *(const bf16x8*)(krow + ((kc * 64 + l4 * 16) ^ sw));
        sv[0][kb] = __builtin_amdgcn_mfma_f32_16x16x32_bf16(qfr[0][kc], kf, sv[0][kb], 0, 0, 0);
        sv[1][kb] = __builtin_amdgcn_mfma_f32_16x16x32_bf16(qfr[1][kc], kf, sv[1][kb], 0, 0, 0);
      }
    }
    // ---- masked online softmax ----
    int kp[4];
#pragma unroll
    for (int kb = 0; kb < 4; kb++) kp[kb] = pos_ids[t0 + kb * 16 + l15];
#pragma unroll
    for (int f = 0; f < 2; f++) {
#pragma unroll
      for (int r = 0; r < 4; r++) {
        int pi = qi[f][r];
        float s0 = ((kp[0] <= pi) && (pi - kp[0] < WIN)) ? sv[f][0][r] : -__builtin_inff();
        float s1 = ((kp[1] <= pi) && (pi - kp[1] < WIN)) ? sv[f][1][r] : -__builtin_inff();
        float s2 = ((kp[2] <= pi) && (pi - kp[2] < WIN)) ? sv[f][2][r] : -__builtin_inff();
        float s3 = ((kp[3] <= pi) && (pi - kp[3] < WIN)) ? sv[f][3][r] : -__builtin_inff();
        float mx = fmaxf(fmaxf(s0, s1), fmaxf(s2, s3));
#pragma unroll
        for (int off = 1; off < 16; off <<= 1) mx = fmaxf(mx, __shfl_xor(mx, off));
        float om = mrow[f][r];
        float nm = fmaxf(om, mx);
        float al = __expf(om - nm);
        mrow[f][r] = nm;
        float e0 = __expf(s0 - nm), e1 = __expf(s1 - nm);
        float e2 = __expf(s2 - nm), e3 = __expf(s3 - nm);
        float sum = (e0 + e1) + (e2 + e3);
#pragma unroll
        for (int off = 1; off < 16; off <<= 1) sum += __shfl_xor(sum, off);
        lrow[f][r] = lrow[f][r] * al + sum;
#pragma unroll
        for (int nd = 0; nd < 16; nd++) acc[f][nd][r] *= al;
        int q = f * 16 + l4 * 4 + r;
        char* lpw = (char*)&lP[wave][0] + q * 128;
        int swp = (q & 7) << 4;
        *(u16*)(lpw + ((l15 * 2) ^ swp)) = f2bf(e0);
        *(u16*)(lpw + ((32 + l15 * 2) ^ swp)) = f2bf(e1);
        *(u16*)(lpw + ((64 + l15 * 2) ^ swp)) = f2bf(e2);
        *(u16*)(lpw + ((96 + l15 * 2) ^ swp)) = f2bf(e3);
      }
    }
    // ---- O += P V ----
#pragma unroll
    for (int kc2 = 0; kc2 < 2; kc2++) {
      bf16x8 pa[2];
#pragma unroll
      for (int f = 0; f < 2; f++) {
        int q = f * 16 + l15;
        pa[f] = *(const bf16x8*)((const char*)&lP[wave][0] + q * 128 +
                                 ((kc2 * 64 + l4 * 16) ^ ((q & 7) << 4)));
      }
#pragma unroll
      for (int nd = 0; nd < 16; nd++) {
        int d = nd * 16 + l15;
        bf16x8 vf = *(const bf16x8*)((const char*)&lV[buf][d * 64] +
                                     ((kc2 * 64 + l4 * 16) ^ ((d & 7) << 4)));
        acc[0][nd] = __builtin_amdgcn_mfma_f32_16x16x32_bf16(pa[0], vf, acc[0][nd], 0, 0, 0);
        acc[1][nd] = __builtin_amdgcn_mfma_f32_16x16x32_bf16(pa[1], vf, acc[1][nd], 0, 0, 0);
      }
    }
    __syncthreads();  // drains vmcnt (next-tile stage done) + all reads of buf done
    buf ^= 1;
  }
  float rinv[2][4];
#pragma unroll
  for (int f = 0; f < 2; f++)
#pragma unroll
    for (int r = 0; r < 4; r++) rinv[f][r] = 1.0f / lrow[f][r];
#pragma unroll
  for (int f = 0; f < 2; f++)
#pragma unroll
    for (int nd = 0; nd < 16; nd++)
#pragma unroll
      for (int r = 0; r < 4; r++) {
        size_t row = qw + f * 16 + l4 * 4 + r;
        aout[row * AO_N + h * HD + nd * 16 + l15] = f2bf(acc[f][nd][r] * rinv[f][r]);
      }
#undef ATTN_STAGE
}

extern "C" void kernel_launch(void* const* d_in, const int* in_sizes, int n_in,
                              void* d_out, int out_size, void* d_ws, size_t ws_size,
                              hipStream_t stream) {
  const float* x = (const float*)d_in[0];
  const int* pos = (const int*)d_in[1];
  const float* wq = (const float*)d_in[2];
  const float* wk = (const float*)d_in[3];
  const float* wv = (const float*)d_in[4];
  const float* wo = (const float*)d_in[5];
  const float* qnw = (const float*)d_in[6];
  const float* knw = (const float*)d_in[7];

  // scratch layout (max 36.7MB of ws, same budget as r0):
  //   d_out: qkv bf16 [4096][4096] (overwritten by final fp32 GEMM)
  //   ws+0        : x bf16 [4096][2304]; later aout bf16 [4096][2048]
  //   ws+18874368 : W^T bf16 (qkv-phase: [4096][2304]; out-phase: wo^T [2304][2048] = 9.4MB)
  //   ws+28311552 : vt bf16 [4][256][4096] (written after QKV GEMM, fits in wT's dead tail)
  u16* qkv = (u16*)d_out;
  u16* xbf = (u16*)d_ws;
  u16* wT = (u16*)((char*)d_ws + 18874368);
  u16* vtb = (u16*)((char*)d_ws + 28311552);
  u16* aout = xbf;

  k_cvt_bf16<<<9216, 256, 0, stream>>>(x, xbf, S_LEN * HID_DIM);
  k_transpose_cvt<<<dim3(64, 72), 256, 0, stream>>>(wq, 2048, wT, HID_DIM, 0);
  k_transpose_cvt<<<dim3(32, 72), 256, 0, stream>>>(wk, 1024, wT, HID_DIM, 2048);
  k_transpose_cvt<<<dim3(32, 72), 256, 0, stream>>>(wv, 1024, wT, HID_DIM, 3072);
  k_gemm_bt<1><<<dim3(32, 32), 256, 0, stream>>>(xbf, wT, qkv, S_LEN, QKV_N, HID_DIM);
  k_vtrans<<<dim3(32, 128), 256, 0, stream>>>(qkv, vtb);
  k_normrope<<<S_LEN * 12, 128, 0, stream>>>(qkv, pos, qnw, knw);
  k_attn<<<dim3(32, 8), 256, 0, stream>>>(qkv, vtb, pos, aout);
  k_transpose_cvt<<<dim3(72, 64), 256, 0, stream>>>(wo, HID_DIM, wT, 2048, 0);
  k_gemm_bt<0><<<dim3(18, 32), 256, 0, stream>>>(aout, wT, d_out, S_LEN, HID_DIM, 2048);
}